// Round 11
// baseline (425.304 us; speedup 1.0000x reference)
//
#include <hip/hip_runtime.h>
#include <stdint.h>
#include <stddef.h>

// ---------------------------------------------------------------------------
// QuantizedLinear: y = x @ (scale*(Wq - zp))^T + bias ; M=8192,N=4096,K=4096
// R11 (= R10 + lgkmcnt fix): 256x256 tile, BK=64, 4 waves x 128x128 wave tile
// (2x2), 1 wave/SIMD (launch_bounds(256,1) -> 512-reg unified budget;
// acc=256 f32). DS-read volume per tile cut 33% vs 8-wave: 128 b128/CU/tile
// ~1536cy + 512cy DMA < MFMA 2480cy -> MFMA-bound.
// 2 phases/tile: {issue 16 ds_reads(ks1)+STAGE(t+1) -> lgkm(15) -> 64 MFMA}
// {lgkm(0)+vmcnt(0)+barrier -> issue next ks0 reads -> 64 MFMA}. Proven
// chunk swizzle c^=(r>>1)&3 both-sides; XCD block swizzle; 16x16x32 layouts.
// NOTE: lgkmcnt is 4-bit (max 15) -> LGKM(15) instead of the intended 16
// (waits one extra Y-read; ~12cy, negligible).
// ---------------------------------------------------------------------------

typedef __attribute__((ext_vector_type(4))) float   f32x4;
typedef __attribute__((ext_vector_type(8))) short   short8;   // 8 x bf16
typedef __attribute__((ext_vector_type(4))) int     i32x4;
typedef __attribute__((ext_vector_type(8))) unsigned short ushort8;
typedef __attribute__((ext_vector_type(4))) unsigned short ushort4v;

__device__ __forceinline__ unsigned short f2bf(float f) {
  union { float f; unsigned u; } v; v.f = f;
  unsigned u = v.u;
  u += 0x7fffu + ((u >> 16) & 1u);      // RNE to bf16
  return (unsigned short)(u >> 16);
}

__device__ __forceinline__ void gld_lds16(const void* g, void* l) {
  __builtin_amdgcn_global_load_lds(
      (const __attribute__((address_space(1))) unsigned int*)g,
      (__attribute__((address_space(3))) unsigned int*)l,
      16, 0, 0);
}

__device__ __forceinline__ unsigned ldsAddr(const void* p) {
  return (unsigned)(size_t)(const __attribute__((address_space(3))) void*)p;
}

__device__ __forceinline__ void wgb() {
  asm volatile("" ::: "memory");
  __builtin_amdgcn_s_barrier();
  asm volatile("" ::: "memory");
}

#define DSR(dst, addr, OFF) \
  asm volatile("ds_read_b128 %0, %1 offset:" #OFF : "=v"(dst) : "v"(addr))
#define LGKM(N) do { asm volatile("s_waitcnt lgkmcnt(" #N ")" ::: "memory"); \
                     __builtin_amdgcn_sched_barrier(0); } while (0)
#define VMCNT(N) do { asm volatile("s_waitcnt vmcnt(" #N ")" ::: "memory"); \
                      __builtin_amdgcn_sched_barrier(0); } while (0)

// ---------- prepass: x fp32 -> bf16 ----------
__global__ __launch_bounds__(256) void cvt_x_kernel(
    const f32x4* __restrict__ x, ushort8* __restrict__ o, int n8) {
  int i = blockIdx.x * 256 + threadIdx.x;
  if (i >= n8) return;
  f32x4 a = x[2 * i], b = x[2 * i + 1];
  ushort8 r;
  r[0] = f2bf(a[0]); r[1] = f2bf(a[1]); r[2] = f2bf(a[2]); r[3] = f2bf(a[3]);
  r[4] = f2bf(b[0]); r[5] = f2bf(b[1]); r[6] = f2bf(b[2]); r[7] = f2bf(b[3]);
  o[i] = r;
}

// ---------- prepass: Wq int32 -> bf16 of (q - zp) ----------
__global__ __launch_bounds__(256) void cvt_w_kernel(
    const i32x4* __restrict__ q, ushort8* __restrict__ o,
    const float* __restrict__ zp_p, int n8) {
  int i = blockIdx.x * 256 + threadIdx.x;
  if (i >= n8) return;
  float zp = zp_p[0];
  i32x4 a = q[2 * i], b = q[2 * i + 1];
  ushort8 r;
  r[0] = f2bf((float)a[0] - zp); r[1] = f2bf((float)a[1] - zp);
  r[2] = f2bf((float)a[2] - zp); r[3] = f2bf((float)a[3] - zp);
  r[4] = f2bf((float)b[0] - zp); r[5] = f2bf((float)b[1] - zp);
  r[6] = f2bf((float)b[2] - zp); r[7] = f2bf((float)b[3] - zp);
  o[i] = r;
}

// ---------------------------------------------------------------------------
// Main 256^2 GEMM, 4-wave 128x128, 2-phase/K-tile pipeline.
// LDS region (buf,kh): [256 rows][32 k] bf16 = 16 KiB; staged linearly;
// logical chunk c of row r stored at position c ^ ((r>>1)&3).
// ---------------------------------------------------------------------------
__global__ __launch_bounds__(256, 1) void qgemm256_kernel(
    const unsigned short* __restrict__ A,   // [M][K] bf16 (x)
    const unsigned short* __restrict__ B,   // [N][K] bf16 (dequant W)
    const float* __restrict__ bias, const float* __restrict__ scale_p,
    float* __restrict__ C, int M, int N, int K) {
  __shared__ __attribute__((aligned(16))) unsigned short sA[2 * 2 * 8192]; // 64KiB
  __shared__ __attribute__((aligned(16))) unsigned short sB[2 * 2 * 8192]; // 64KiB

  const int tid  = threadIdx.x;
  const int lane = tid & 63;
  const int w    = tid >> 6;         // 0..3
  const int wr   = w >> 1;           // 0..1  (M strip of 128)
  const int wc   = w & 1;            // 0..1  (N strip of 128)

  // XCD-aware block swizzle (bijective when nwg % 8 == 0)
  const int nwg = gridDim.x;
  const int bid = blockIdx.x;
  const int swz = ((nwg & 7) == 0) ? ((bid & 7) * (nwg >> 3) + (bid >> 3)) : bid;
  const int ntn = N >> 8;
  const int bm0 = (swz / ntn) << 8;
  const int bn0 = (swz % ntn) << 8;

  const int l16 = lane & 15;
  const int l4  = lane >> 4;                       // 0..3 -> k chunk
  const int rchk = (l4 ^ ((l16 >> 1) & 3)) << 4;   // swizzled chunk byte off

  // per-lane LDS read byte bases within a 16 KiB (buf,kh) region
  const unsigned aBase = (unsigned)((wr * 128 + l16) * 64 + rchk);
  const unsigned bBase = (unsigned)((wc * 128 + l16) * 64 + rchk);
  const unsigned sAaddr = ldsAddr(sA);
  const unsigned sBaddr = ldsAddr(sB);

  // staging (256 threads): chunk id = i*256+tid (i=0..3) per region;
  // row = 64*i + (tid>>2); stored pos = tid&3; src chunk = pos ^ ((row>>1)&3)
  const int rbase = tid >> 2;
  const int csrc  = (((tid & 3) ^ ((tid >> 3) & 3)) << 3);  // src k-elems

  const unsigned short* Ab = A + (size_t)bm0 * K;
  const unsigned short* Bb = B + (size_t)bn0 * K;

  f32x4 acc[8][8] = {};
  const int nkt = K >> 6;

  // STAGE(T): tile T's 4 regions (A kh0/kh1, B kh0/kh1), 16 gld/thread
#define STAGE(T) do {                                                    \
    const int _nx = (T) & 1; const int _k = (T) << 6;                    \
    unsigned short* _dA0 = sA + (((_nx << 1) + 0) << 13);                \
    unsigned short* _dA1 = sA + (((_nx << 1) + 1) << 13);                \
    unsigned short* _dB0 = sB + (((_nx << 1) + 0) << 13);                \
    unsigned short* _dB1 = sB + (((_nx << 1) + 1) << 13);                \
    _Pragma("unroll")                                                    \
    for (int i = 0; i < 4; ++i) {                                        \
      const size_t _r = (size_t)(64 * i + rbase) * K;                    \
      const int _d = ((i * 256 + tid) << 3);                             \
      gld_lds16(Ab + _r + _k + csrc,      _dA0 + _d);                    \
      gld_lds16(Ab + _r + _k + 32 + csrc, _dA1 + _d);                    \
      gld_lds16(Bb + _r + _k + csrc,      _dB0 + _d);                    \
      gld_lds16(Bb + _r + _k + 32 + csrc, _dB1 + _d);                    \
    }                                                                    \
  } while (0)

  // issue all 8 A-frags + 8 B-frags of region RG (16 DSR)
#define ISSUE(AS, BS, RG) do {                                           \
    unsigned _a = sAaddr + ((unsigned)(RG) << 14) + aBase;               \
    unsigned _b = sBaddr + ((unsigned)(RG) << 14) + bBase;               \
    DSR(AS[0], _a, 0);    DSR(AS[1], _a, 1024);                          \
    DSR(AS[2], _a, 2048); DSR(AS[3], _a, 3072);                          \
    DSR(AS[4], _a, 4096); DSR(AS[5], _a, 5120);                          \
    DSR(AS[6], _a, 6144); DSR(AS[7], _a, 7168);                          \
    DSR(BS[0], _b, 0);    DSR(BS[1], _b, 1024);                          \
    DSR(BS[2], _b, 2048); DSR(BS[3], _b, 3072);                          \
    DSR(BS[4], _b, 4096); DSR(BS[5], _b, 5120);                          \
    DSR(BS[6], _b, 6144); DSR(BS[7], _b, 7168);                          \
  } while (0)

#define MM64(AS, BS) do { __builtin_amdgcn_s_setprio(1);                       \
    _Pragma("unroll") for (int m = 0; m < 8; ++m)                              \
    _Pragma("unroll") for (int n = 0; n < 8; ++n)                              \
      acc[m][n] = __builtin_amdgcn_mfma_f32_16x16x32_bf16(AS[m], BS[n], acc[m][n], 0, 0, 0); \
    __builtin_amdgcn_s_setprio(0); } while (0)

  short8 aX[8], bX[8], aY[8], bY[8];

  // ---- prologue: stage tile0; issue (tile0, kh0) reads ----
  STAGE(0);
  VMCNT(0);
  wgb();
  ISSUE(aX, bX, 0);

  for (int kt = 0; kt < nkt; ++kt) {
    const int cur = kt & 1;
    const int rg1 = (cur << 1) + 1;
    const int nrg0 = (cur ^ 1) << 1;
    const bool pf = (kt + 1 < nkt);

    // ---- P0: issue ks1 reads; stage t+1; MFMA ks0 ----
    ISSUE(aY, bY, rg1);            // 16 DSR (32 outstanding)
    if (pf) STAGE(kt + 1);         // 16 gld (vm only)
    LGKM(15);                      // X resident (+1 Y read); rest drain under MFMA
    MM64(aX, bX);                  // 64 MFMA (~1240 cy)

    // ---- P1: tile boundary; MFMA ks1 ----
    if (pf) {
      LGKM(0);                     // Y resident; all own reads done (WAR-safe)
      VMCNT(0);                    // stage t+1 resident (issued ~1240 cy ago)
      wgb();                       // cross-wave visibility
      ISSUE(aX, bX, nrg0);         // next tile ks0 reads drain under MFMA
    } else {
      LGKM(0);
    }
    MM64(aY, bY);
  }
#undef MM64
#undef ISSUE
#undef STAGE

  // ---- epilogue: y = scale*acc + bias ----
  const float s = scale_p[0];
#pragma unroll
  for (int nf = 0; nf < 8; ++nf) {
    const int col = bn0 + wc * 128 + nf * 16 + l16;
    const float bv = bias[col];
#pragma unroll
    for (int mf = 0; mf < 8; ++mf) {
      const int row0 = bm0 + wr * 128 + mf * 16 + (l4 << 2);
#pragma unroll
      for (int j = 0; j < 4; ++j)
        C[(size_t)(row0 + j) * N + col] = fmaf(s, acc[mf][nf][j], bv);
    }
  }
}

// ---------------------------------------------------------------------------
// Fallback (no workspace): R1's fused 128^2 kernel.
// ---------------------------------------------------------------------------
__global__ __launch_bounds__(256) void qgemm_fused_kernel(
    const float* __restrict__ A, const int* __restrict__ B,
    const float* __restrict__ bias, const float* __restrict__ scale_p,
    const float* __restrict__ zp_p, float* __restrict__ C,
    int M, int N, int K) {
  constexpr int BK = 32;
  __shared__ unsigned short sAf[128 * BK];
  __shared__ unsigned short sBf[128 * BK];
  const int tid = threadIdx.x, lane = tid & 63, w = tid >> 6;
  const int wr = w >> 1, wc = w & 1;
  const int bm0 = blockIdx.y * 128, bn0 = blockIdx.x * 128;
  const int l16 = lane & 15, lk = (lane >> 4) << 3;
  const float zp = zp_p[0];
  f32x4 acc[4][4] = {};
  for (int k0 = 0; k0 < K; k0 += BK) {
#pragma unroll
    for (int c = 0; c < 4; ++c) {
      int ch = c * 256 + tid;
      int row = ch >> 3, c4 = (ch & 7) << 2;
      f32x4 av = *(const f32x4*)(A + (size_t)(bm0 + row) * K + k0 + c4);
      i32x4 bv = *(const i32x4*)(B + (size_t)(bn0 + row) * K + k0 + c4);
      ushort4v ra, rb;
      ra[0] = f2bf(av[0]); ra[1] = f2bf(av[1]); ra[2] = f2bf(av[2]); ra[3] = f2bf(av[3]);
      rb[0] = f2bf((float)bv[0] - zp); rb[1] = f2bf((float)bv[1] - zp);
      rb[2] = f2bf((float)bv[2] - zp); rb[3] = f2bf((float)bv[3] - zp);
      *(ushort4v*)&sAf[row * BK + c4] = ra;
      *(ushort4v*)&sBf[row * BK + c4] = rb;
    }
    __syncthreads();
    short8 a[4], b[4];
#pragma unroll
    for (int m = 0; m < 4; ++m) a[m] = *(const short8*)&sAf[(wr * 64 + m * 16 + l16) * BK + lk];
#pragma unroll
    for (int n = 0; n < 4; ++n) b[n] = *(const short8*)&sBf[(wc * 64 + n * 16 + l16) * BK + lk];
#pragma unroll
    for (int m = 0; m < 4; ++m)
#pragma unroll
      for (int n = 0; n < 4; ++n)
        acc[m][n] = __builtin_amdgcn_mfma_f32_16x16x32_bf16(a[m], b[n], acc[m][n], 0, 0, 0);
    __syncthreads();
  }
  const float s = scale_p[0];
#pragma unroll
  for (int n = 0; n < 4; ++n) {
    const int col = bn0 + wc * 64 + n * 16 + l16;
    const float bv = bias[col];
#pragma unroll
    for (int m = 0; m < 4; ++m) {
      const int row0 = bm0 + wr * 64 + m * 16 + ((lane >> 4) << 2);
#pragma unroll
      for (int j = 0; j < 4; ++j)
        C[(size_t)(row0 + j) * N + col] = fmaf(s, acc[m][n][j], bv);
    }
  }
}

extern "C" void kernel_launch(void* const* d_in, const int* in_sizes, int n_in,
                              void* d_out, int out_size, void* d_ws, size_t ws_size,
                              hipStream_t stream) {
  const float* x     = (const float*)d_in[0];
  const int*   wq    = (const int*)d_in[1];
  const float* bias  = (const float*)d_in[2];
  const float* scale = (const float*)d_in[3];
  const float* zp    = (const float*)d_in[4];
  float*       out   = (float*)d_out;

  const int K = 4096;
  const int N = in_sizes[1] / K;      // 4096
  const int M = in_sizes[0] / K;      // 8192

  const size_t xb_elems = (size_t)M * K;
  const size_t wb_elems = (size_t)N * K;
  const size_t need = (xb_elems + wb_elems) * sizeof(unsigned short);

  if (ws_size >= need && (M % 256 == 0) && (N % 256 == 0) && (K % 64 == 0)) {
    unsigned short* xb = (unsigned short*)d_ws;
    unsigned short* wb = xb + xb_elems;
    int nx8 = (int)(xb_elems / 8), nw8 = (int)(wb_elems / 8);
    cvt_x_kernel<<<(nx8 + 255) / 256, 256, 0, stream>>>((const f32x4*)x, (ushort8*)xb, nx8);
    cvt_w_kernel<<<(nw8 + 255) / 256, 256, 0, stream>>>((const i32x4*)wq, (ushort8*)wb, zp, nw8);
    dim3 grid((M >> 8) * (N >> 8));
    qgemm256_kernel<<<grid, 256, 0, stream>>>(xb, wb, bias, scale, out, M, N, K);
  } else {
    dim3 grid(N / 128, M / 128);
    qgemm_fused_kernel<<<grid, 256, 0, stream>>>(x, wq, bias, scale, zp, out, M, N, K);
  }
}

// Round 12
// 181.839 us; speedup vs baseline: 2.3389x; 2.3389x over previous
//
#include <hip/hip_runtime.h>
#include <stdint.h>
#include <stddef.h>

// ---------------------------------------------------------------------------
// QuantizedLinear: y = x @ (scale*(Wq - zp))^T + bias ; M=8192,N=4096,K=4096
// R12: INT8 port of the best (R8) schedule. (Wq-128) is EXACT in i8; x is
// quantized per-row (s_r = rowmax/127, fused rowmax+quant prepass).
// GEMM: 256x256 tile, K-tile = 128 i8 (2 k-halves of 64B rows), 8 waves
// (2Mx4N), dbuf LDS (proven zero-conflict byte swizzle; row = 64B in both
// bf16 and i8 so ALL byte addressing is identical to R8), one-sub-phase-
// ahead register pipeline, 1 barrier/tile, counted lgkm/vmcnt, setprio.
// mfma_i32_16x16x64_i8: same 4-VGPR operands / 16B-per-lane / C-layout as
// 16x16x32 bf16 (dtype-independent). Epilogue: y = scale*s_r[row]*acc + bias.
// ---------------------------------------------------------------------------

typedef __attribute__((ext_vector_type(4))) float   f32x4;
typedef __attribute__((ext_vector_type(4))) int     i32x4;
typedef __attribute__((ext_vector_type(8))) short   short8;
typedef __attribute__((ext_vector_type(4))) unsigned short ushort4v;
typedef __attribute__((ext_vector_type(2))) unsigned uint2v;

__device__ __forceinline__ unsigned short f2bf(float f) {
  union { float f; unsigned u; } v; v.f = f;
  unsigned u = v.u;
  u += 0x7fffu + ((u >> 16) & 1u);
  return (unsigned short)(u >> 16);
}

__device__ __forceinline__ void gld_lds16(const void* g, void* l) {
  __builtin_amdgcn_global_load_lds(
      (const __attribute__((address_space(1))) unsigned int*)g,
      (__attribute__((address_space(3))) unsigned int*)l,
      16, 0, 0);
}

__device__ __forceinline__ unsigned ldsAddr(const void* p) {
  return (unsigned)(size_t)(const __attribute__((address_space(3))) void*)p;
}

__device__ __forceinline__ void wgb() {
  asm volatile("" ::: "memory");
  __builtin_amdgcn_s_barrier();
  asm volatile("" ::: "memory");
}

#define DSR(dst, addr, OFF) \
  asm volatile("ds_read_b128 %0, %1 offset:" #OFF : "=v"(dst) : "v"(addr))
#define LGKM(N) do { asm volatile("s_waitcnt lgkmcnt(" #N ")" ::: "memory"); \
                     __builtin_amdgcn_sched_barrier(0); } while (0)
#define VMCNT(N) do { asm volatile("s_waitcnt vmcnt(" #N ")" ::: "memory"); \
                      __builtin_amdgcn_sched_barrier(0); } while (0)

// ---------- prepass: Wq int32 -> i8 (q - 128), exact ----------
__global__ __launch_bounds__(256) void cvt_w8_kernel(
    const i32x4* __restrict__ q, uint2v* __restrict__ o, int n8) {
  int i = blockIdx.x * 256 + threadIdx.x;
  if (i >= n8) return;
  i32x4 a = q[2 * i], b = q[2 * i + 1];
  unsigned lo = ((unsigned)((a[0] - 128) & 255)) |
                ((unsigned)((a[1] - 128) & 255) << 8) |
                ((unsigned)((a[2] - 128) & 255) << 16) |
                ((unsigned)((a[3] - 128) & 255) << 24);
  unsigned hi = ((unsigned)((b[0] - 128) & 255)) |
                ((unsigned)((b[1] - 128) & 255) << 8) |
                ((unsigned)((b[2] - 128) & 255) << 16) |
                ((unsigned)((b[3] - 128) & 255) << 24);
  uint2v r; r[0] = lo; r[1] = hi;
  o[i] = r;
}

// ---------- prepass: x fp32 -> i8 with per-row scale (fused rowmax+quant) --
// One block per row (K == 4096). Thread t handles elems t*4 + i*1024, i=0..3.
__global__ __launch_bounds__(256) void quant_x_kernel(
    const float* __restrict__ x, unsigned char* __restrict__ xq,
    float* __restrict__ sr, int K) {
  const int row = blockIdx.x;
  const int tid = threadIdx.x;
  const float* xr = x + (size_t)row * K;

  f32x4 v[4];
  float mx = 0.f;
#pragma unroll
  for (int i = 0; i < 4; ++i) {
    v[i] = *(const f32x4*)(xr + tid * 4 + i * 1024);
#pragma unroll
    for (int j = 0; j < 4; ++j) mx = fmaxf(mx, fabsf(v[i][j]));
  }
  // wave reduce (64 lanes)
#pragma unroll
  for (int off = 32; off >= 1; off >>= 1)
    mx = fmaxf(mx, __shfl_xor(mx, off, 64));
  __shared__ float wmax[4];
  const int wid = tid >> 6;
  if ((tid & 63) == 0) wmax[wid] = mx;
  __syncthreads();
  const float m = fmaxf(fmaxf(wmax[0], wmax[1]), fmaxf(wmax[2], wmax[3]));
  const float inv = (m > 0.f) ? (127.f / m) : 0.f;
  if (tid == 0) sr[row] = (m > 0.f) ? (m / 127.f) : 1.f;

  unsigned char* xo = xq + (size_t)row * K;
#pragma unroll
  for (int i = 0; i < 4; ++i) {
    int q0 = __float2int_rn(v[i][0] * inv);
    int q1 = __float2int_rn(v[i][1] * inv);
    int q2 = __float2int_rn(v[i][2] * inv);
    int q3 = __float2int_rn(v[i][3] * inv);
    unsigned p = ((unsigned)(q0 & 255)) | ((unsigned)(q1 & 255) << 8) |
                 ((unsigned)(q2 & 255) << 16) | ((unsigned)(q3 & 255) << 24);
    *(unsigned*)(xo + tid * 4 + i * 1024) = p;
  }
}

// ---------------------------------------------------------------------------
// Main 256^2 i8 GEMM (R8 schedule, byte-identical LDS geometry).
// LDS region (buf,kh): [256 rows][64 B] = 16 KiB; logical 16B-chunk c of
// row r stored at position c ^ ((r>>1)&3) (both-sides, proven 0-conflict).
// K-tile = 128 i8 = kh0 (64B) + kh1 (64B). nkt = K/128.
// ---------------------------------------------------------------------------
__global__ __launch_bounds__(512, 2) void qgemm256_i8_kernel(
    const unsigned char* __restrict__ A,   // [M][K] i8 (x quantized)
    const unsigned char* __restrict__ B,   // [N][K] i8 (Wq - 128)
    const float* __restrict__ bias, const float* __restrict__ scale_p,
    const float* __restrict__ sr, float* __restrict__ C,
    int M, int N, int K) {
  __shared__ __attribute__((aligned(16))) unsigned char sA[2 * 2 * 16384]; // 64KiB
  __shared__ __attribute__((aligned(16))) unsigned char sB[2 * 2 * 16384]; // 64KiB

  const int tid  = threadIdx.x;
  const int lane = tid & 63;
  const int w    = tid >> 6;         // 0..7
  const int wr   = w >> 2;           // 0..1  (M strip of 128)
  const int wc   = w & 3;            // 0..3  (N strip of 64)

  // XCD-aware block swizzle (bijective when nwg % 8 == 0)
  const int nwg = gridDim.x;
  const int bid = blockIdx.x;
  const int swz = ((nwg & 7) == 0) ? ((bid & 7) * (nwg >> 3) + (bid >> 3)) : bid;
  const int ntn = N >> 8;
  const int bm0 = (swz / ntn) << 8;
  const int bn0 = (swz % ntn) << 8;

  const int l16 = lane & 15;
  const int l4  = lane >> 4;                       // 0..3 -> 16B k-chunk
  const int rchk = (l4 ^ ((l16 >> 1) & 3)) << 4;   // swizzled chunk byte off

  // per-lane LDS read byte bases within a 16 KiB (buf,kh) region (row=64B)
  const unsigned aBase = (unsigned)((wr * 128 + l16) * 64 + rchk);
  const unsigned bBase = (unsigned)((wc * 64 + l16) * 64 + rchk);
  const unsigned sAaddr = ldsAddr(sA);
  const unsigned sBaddr = ldsAddr(sB);

  // staging: thread covers rows (tid>>2), (tid>>2)+128; one 16B chunk each.
  // stored chunk pos = tid&3; src chunk = pos ^ ((row>>1)&3), row&2 = tid&... :
  // row = tid>>2 -> (row>>1)&3 = (tid>>3)&3  (same derivation as R8)
  const int    st0b = tid << 4, st1b = (tid + 512) << 4;
  const size_t rK0  = (size_t)(tid >> 2) * K;
  const size_t rK1  = (size_t)((tid >> 2) + 128) * K;
  const int    csrc = (((tid & 3) ^ ((tid >> 3) & 3)) << 4);  // src byte off

  const unsigned char* Ab = A + (size_t)bm0 * K;
  const unsigned char* Bb = B + (size_t)bn0 * K;

  i32x4 acc[8][4] = {};
  const int nkt = K >> 7;            // 128 i8 per K-tile

  // STAGE(T): tile T's 4 regions (A kh0/kh1, B kh0/kh1), 8 gld/thread
#define STAGE(T) do {                                                    \
    const int _nx = (T) & 1; const int _k = (T) << 7;                    \
    unsigned char* _dA0 = sA + (((_nx << 1) + 0) << 14);                 \
    unsigned char* _dA1 = sA + (((_nx << 1) + 1) << 14);                 \
    unsigned char* _dB0 = sB + (((_nx << 1) + 0) << 14);                 \
    unsigned char* _dB1 = sB + (((_nx << 1) + 1) << 14);                 \
    gld_lds16(Ab + rK0 + _k + csrc,      _dA0 + st0b);                   \
    gld_lds16(Ab + rK1 + _k + csrc,      _dA0 + st1b);                   \
    gld_lds16(Ab + rK0 + _k + 64 + csrc, _dA1 + st0b);                   \
    gld_lds16(Ab + rK1 + _k + 64 + csrc, _dA1 + st1b);                   \
    gld_lds16(Bb + rK0 + _k + csrc,      _dB0 + st0b);                   \
    gld_lds16(Bb + rK1 + _k + csrc,      _dB0 + st1b);                   \
    gld_lds16(Bb + rK0 + _k + 64 + csrc, _dB1 + st0b);                   \
    gld_lds16(Bb + rK1 + _k + 64 + csrc, _dB1 + st1b);                   \
  } while (0)

  // issue a-lo (m0-3) + b fragments of region RG (8 DSR)
#define ISSUE_AB(AS, BS, RG) do {                                        \
    unsigned _a = sAaddr + ((unsigned)(RG) << 14) + aBase;               \
    unsigned _b = sBaddr + ((unsigned)(RG) << 14) + bBase;               \
    DSR(AS[0], _a, 0); DSR(AS[1], _a, 1024);                             \
    DSR(AS[2], _a, 2048); DSR(AS[3], _a, 3072);                          \
    DSR(BS[0], _b, 0); DSR(BS[1], _b, 1024);                             \
    DSR(BS[2], _b, 2048); DSR(BS[3], _b, 3072);                          \
  } while (0)

  // issue a-hi (m4-7) of region RG into a2 (4 DSR)
#define ISSUE_A2(RG) do {                                                \
    unsigned _a = sAaddr + ((unsigned)(RG) << 14) + aBase;               \
    DSR(a2[0], _a, 4096); DSR(a2[1], _a, 5120);                          \
    DSR(a2[2], _a, 6144); DSR(a2[3], _a, 7168);                          \
  } while (0)

#define MMLO(AS, BS) do { __builtin_amdgcn_s_setprio(1);                       \
    _Pragma("unroll") for (int m = 0; m < 4; ++m)                              \
    _Pragma("unroll") for (int n = 0; n < 4; ++n)                              \
      acc[m][n] = __builtin_amdgcn_mfma_i32_16x16x64_i8(AS[m], BS[n], acc[m][n], 0, 0, 0); \
    __builtin_amdgcn_s_setprio(0); } while (0)
#define MMHI(BS) do { __builtin_amdgcn_s_setprio(1);                           \
    _Pragma("unroll") for (int m = 0; m < 4; ++m)                              \
    _Pragma("unroll") for (int n = 0; n < 4; ++n)                              \
      acc[4 + m][n] = __builtin_amdgcn_mfma_i32_16x16x64_i8(a2[m], BS[n], acc[4 + m][n], 0, 0, 0); \
    __builtin_amdgcn_s_setprio(0); } while (0)

  i32x4 aX[4], bX[4], aY[4], bY[4], a2[4];

  // ---- prologue: stage tile0; issue ab(0,kh0) into X ----
  STAGE(0);
  VMCNT(0);
  wgb();
  ISSUE_AB(aX, bX, 0);

  for (int kt = 0; kt < nkt; ++kt) {
    const int cur = kt & 1;
    const int rg0 = cur << 1, rg1 = rg0 + 1;
    const int nrg0 = (cur ^ 1) << 1;
    const bool pf = (kt + 1 < nkt);

    // ---- kh0.P0: prefetch a2(kh0); stage t+1; MFMA lo(kh0) ----
    ISSUE_A2(rg0);                 // outstanding: abX 8 + a2 4 = 12
    if (pf) STAGE(kt + 1);         // 8 gld (vmcnt only)
    LGKM(4);                       // abX resident; a2 drains under MFMA
    MMLO(aX, bX);

    // ---- kh0.P1: prefetch ab(kh1) into Y; MFMA hi(kh0) ----
    ISSUE_AB(aY, bY, rg1);         // outstanding: a2 4 + abY 8 = 12
    LGKM(8);                       // a2 resident; abY drains under MFMA
    MMHI(bX);

    // ---- kh1.P0: prefetch a2(kh1); MFMA lo(kh1) ----
    ISSUE_A2(rg1);                 // outstanding: abY 8 + a2 4 = 12
    LGKM(4);                       // abY resident
    MMLO(aY, bY);

    // ---- kh1.P1: tile boundary; MFMA hi(kh1) ----
    if (pf) {
      LGKM(0);                     // all own reads done -> WAR-safe
      VMCNT(0);                    // tile t+1 resident (staged 3 sub-phases ago)
      wgb();                       // cross-wave visibility
      ISSUE_AB(aX, bX, nrg0);      // prefetch (t+1, kh0) across the MFMA
    } else {
      LGKM(0);
    }
    MMHI(bY);
  }
#undef MMHI
#undef MMLO
#undef ISSUE_A2
#undef ISSUE_AB
#undef STAGE

  // ---- epilogue: y = scale * sr[row] * acc + bias ----
  const float s = scale_p[0];
#pragma unroll
  for (int mf = 0; mf < 8; ++mf) {
    const int row0 = bm0 + wr * 128 + mf * 16 + (l4 << 2);
    const f32x4 s4 = *(const f32x4*)(sr + row0);   // rows row0..row0+3
#pragma unroll
    for (int nf = 0; nf < 4; ++nf) {
      const int col = bn0 + wc * 64 + nf * 16 + l16;
      const float bv = bias[col];
#pragma unroll
      for (int j = 0; j < 4; ++j)
        C[(size_t)(row0 + j) * N + col] =
            fmaf(s * s4[j], (float)acc[mf][nf][j], bv);
    }
  }
}

// ---------------------------------------------------------------------------
// Fallback (no workspace / odd shapes): fused bf16 128^2 kernel (R1).
// ---------------------------------------------------------------------------
__global__ __launch_bounds__(256) void qgemm_fused_kernel(
    const float* __restrict__ A, const int* __restrict__ B,
    const float* __restrict__ bias, const float* __restrict__ scale_p,
    const float* __restrict__ zp_p, float* __restrict__ C,
    int M, int N, int K) {
  constexpr int BK = 32;
  __shared__ unsigned short sAf[128 * BK];
  __shared__ unsigned short sBf[128 * BK];
  const int tid = threadIdx.x, lane = tid & 63, w = tid >> 6;
  const int wr = w >> 1, wc = w & 1;
  const int bm0 = blockIdx.y * 128, bn0 = blockIdx.x * 128;
  const int l16 = lane & 15, lk = (lane >> 4) << 3;
  const float zp = zp_p[0];
  f32x4 acc[4][4] = {};
  for (int k0 = 0; k0 < K; k0 += BK) {
#pragma unroll
    for (int c = 0; c < 4; ++c) {
      int ch = c * 256 + tid;
      int row = ch >> 3, c4 = (ch & 7) << 2;
      f32x4 av = *(const f32x4*)(A + (size_t)(bm0 + row) * K + k0 + c4);
      i32x4 bv = *(const i32x4*)(B + (size_t)(bn0 + row) * K + k0 + c4);
      ushort4v ra, rb;
      ra[0] = f2bf(av[0]); ra[1] = f2bf(av[1]); ra[2] = f2bf(av[2]); ra[3] = f2bf(av[3]);
      rb[0] = f2bf((float)bv[0] - zp); rb[1] = f2bf((float)bv[1] - zp);
      rb[2] = f2bf((float)bv[2] - zp); rb[3] = f2bf((float)bv[3] - zp);
      *(ushort4v*)&sAf[row * BK + c4] = ra;
      *(ushort4v*)&sBf[row * BK + c4] = rb;
    }
    __syncthreads();
    short8 a[4], b[4];
#pragma unroll
    for (int m = 0; m < 4; ++m) a[m] = *(const short8*)&sAf[(wr * 64 + m * 16 + l16) * BK + lk];
#pragma unroll
    for (int n = 0; n < 4; ++n) b[n] = *(const short8*)&sBf[(wc * 64 + n * 16 + l16) * BK + lk];
#pragma unroll
    for (int m = 0; m < 4; ++m)
#pragma unroll
      for (int n = 0; n < 4; ++n)
        acc[m][n] = __builtin_amdgcn_mfma_f32_16x16x32_bf16(a[m], b[n], acc[m][n], 0, 0, 0);
    __syncthreads();
  }
  const float s = scale_p[0];
#pragma unroll
  for (int n = 0; n < 4; ++n) {
    const int col = bn0 + wc * 64 + n * 16 + l16;
    const float bv = bias[col];
#pragma unroll
    for (int m = 0; m < 4; ++m) {
      const int row0 = bm0 + wr * 64 + m * 16 + ((lane >> 4) << 2);
#pragma unroll
      for (int j = 0; j < 4; ++j)
        C[(size_t)(row0 + j) * N + col] = fmaf(s, acc[m][n][j], bv);
    }
  }
}

extern "C" void kernel_launch(void* const* d_in, const int* in_sizes, int n_in,
                              void* d_out, int out_size, void* d_ws, size_t ws_size,
                              hipStream_t stream) {
  const float* x     = (const float*)d_in[0];
  const int*   wq    = (const int*)d_in[1];
  const float* bias  = (const float*)d_in[2];
  const float* scale = (const float*)d_in[3];
  const float* zp    = (const float*)d_in[4];
  float*       out   = (float*)d_out;

  const int K = 4096;
  const int N = in_sizes[1] / K;      // 4096
  const int M = in_sizes[0] / K;      // 8192

  const size_t xq_bytes = (size_t)M * K;          // i8 x
  const size_t wq_bytes = (size_t)N * K;          // i8 w
  const size_t sr_bytes = (size_t)M * sizeof(float);
  const size_t need = xq_bytes + wq_bytes + sr_bytes;

  if (ws_size >= need && K == 4096 &&
      (M % 256 == 0) && (N % 256 == 0)) {
    unsigned char* xq = (unsigned char*)d_ws;
    unsigned char* w8 = xq + xq_bytes;
    float*         sr = (float*)(w8 + wq_bytes);

    int nw8 = (int)(wq_bytes / 8);
    cvt_w8_kernel<<<(nw8 + 255) / 256, 256, 0, stream>>>(
        (const i32x4*)wq, (uint2v*)w8, nw8);
    quant_x_kernel<<<M, 256, 0, stream>>>(x, xq, sr, K);

    dim3 grid((M >> 8) * (N >> 8));
    qgemm256_i8_kernel<<<grid, 512, 0, stream>>>(
        xq, w8, bias, scale, sr, out, M, N, K);
  } else {
    dim3 grid(N / 128, M / 128);
    qgemm_fused_kernel<<<grid, 256, 0, stream>>>(x, wq, bias, scale, zp, out, M, N, K);
  }
}